// Round 5
// baseline (397.102 us; speedup 1.0000x reference)
//
#include <hip/hip_runtime.h>

// Problem geometry (fixed by the reference): B=8, H=1024, W=1024, periodic.
#define WMASK 1023
#define LOG2W 10
#define HW (1024 * 1024)

#define EPS 1e-6f
#define DT 1e-2f

// Output tile 64x16, 256 threads, 1 float4 of output per thread per tile.
// Each block sweeps TPB=4 vertically-adjacent tiles, pipelining the staging:
//   compute tile n  |  regs hold tile n+1  |  global loads for tile n+2 in flight.
#define TX 64
#define TY 16
#define TPB 4

// Raw tiles in one contiguous LDS pool, f4-task-indexed:
//   cv  tasks [0,360):   x [x0-4,x0+67] (18 chunks, stride 72), y [y0-2,y0+17] (20 rows)
//   ci  tasks [360,720): same
//   eta tasks [720,1044): y [y0-1,y0+16] (18 rows)
// float offset of task r within field = 4*r exactly (18*4 == 72 == row stride).
#define RST 72
#define NTASK 1044
// dF tiles: interior only, 16 chunks x 16 rows, dense stride 64.
#define SST 64
// LDS: 1044*16 + 2*16*64*4 = 16704 + 8192 = 24896 B -> 6 blocks/CU.

typedef float f4 __attribute__((ext_vector_type(4)));

struct Stage { f4 v0, v1, v2, v3, v4; };

__device__ __forceinline__ float scal(const float* __restrict__ p) {
    return fabsf(p[0]) + 0.001f;
}
__device__ __forceinline__ float clip01(float v) {
    return fminf(fmaxf(v, 0.0f), 1.0f);
}
// log2 of clamped arg; caller folds ln2 into the kBT scalar (kl).
__device__ __forceinline__ float lg2m(float m) {
    return __log2f(fmaxf(m, EPS));   // jnp.log(where(m<eps,eps,m)) == ln2*log2(max(m,eps))
}

// Barrier WITHOUT the vmcnt(0) drain __syncthreads() would emit: waits only
// for this wave's LDS ops, then syncs. Prefetch global loads stay in flight.
__device__ __forceinline__ void lgkm_barrier() {
    asm volatile("s_waitcnt lgkmcnt(0)" ::: "memory");
    __builtin_amdgcn_s_barrier();
}

__device__ __forceinline__ f4 ld_task(int t, int x0, int y0t, int bbase,
                                      const float* __restrict__ cv,
                                      const float* __restrict__ ci,
                                      const float* __restrict__ eta) {
    const float* __restrict__ src;
    int r, gy0;
    if (t < 360)      { src = cv;  r = t;       gy0 = y0t - 2; }
    else if (t < 720) { src = ci;  r = t - 360; gy0 = y0t - 2; }
    else              { src = eta; r = t - 720; gy0 = y0t - 1; }
    const int cx = r % 18;
    const int cy = r / 18;
    const int gx = (x0 - 4 + (cx << 2)) & WMASK;   // 4-aligned, no row-cross
    const int gy = (gy0 + cy) & WMASK;
    return *(const f4*)(src + bbase + (gy << LOG2W) + gx);
}

__global__ __launch_bounds__(256, 6) void irr_fused(
    const float* __restrict__ cv,
    const float* __restrict__ ci,
    const float* __restrict__ eta,
    const float* __restrict__ p_ev,
    const float* __restrict__ p_ei,
    const float* __restrict__ p_kbt,
    const float* __restrict__ p_kv,
    const float* __restrict__ p_ki,
    const float* __restrict__ p_ke,
    const float* __restrict__ p_dv,
    const float* __restrict__ p_di,
    const float* __restrict__ p_L,
    float* __restrict__ cv_new,
    float* __restrict__ ci_new,
    float* __restrict__ eta_new)
{
    __shared__ __attribute__((aligned(16))) float sraw[NTASK * 4];
    __shared__ __attribute__((aligned(16))) float sdv[16][SST];
    __shared__ __attribute__((aligned(16))) float sdi[16][SST];

    float (*scv)[RST]  = (float(*)[RST])(sraw);
    float (*sci)[RST]  = (float(*)[RST])(sraw + 1440);
    float (*seta)[RST] = (float(*)[RST])(sraw + 2880);

    const int tid = threadIdx.x;
    const int x0 = blockIdx.x * TX;
    const int y0 = blockIdx.y * (TY * TPB);
    const int bbase = blockIdx.z * HW;

    const float energy_v = scal(p_ev);
    const float energy_i = scal(p_ei);
    const float kBT      = scal(p_kbt);
    const float kappa_v  = scal(p_kv);
    const float kappa_i  = scal(p_ki);
    const float kappa_e  = scal(p_ke);
    const float diff_v   = scal(p_dv);
    const float diff_i   = scal(p_di);
    const float L        = scal(p_L);
    const float kl   = kBT * 0.69314718056f;   // kBT*ln2: folds log2->ln
    const float dtl  = DT * L;
    const float dtrv = DT * diff_v / kBT;      // DT * mv / cv
    const float dtri = DT * diff_i / kBT;

    auto load_tile = [&](int y0t) -> Stage {
        Stage s;
        s.v0 = ld_task(tid,       x0, y0t, bbase, cv, ci, eta);
        s.v1 = ld_task(tid + 256, x0, y0t, bbase, cv, ci, eta);
        s.v2 = ld_task(tid + 512, x0, y0t, bbase, cv, ci, eta);
        s.v3 = ld_task(tid + 768, x0, y0t, bbase, cv, ci, eta);
        if (tid < NTASK - 1024)
            s.v4 = ld_task(tid + 1024, x0, y0t, bbase, cv, ci, eta);
        return s;
    };
    auto store_stage = [&](const Stage& s) {
        f4* dst = (f4*)sraw;
        dst[tid]       = s.v0;
        dst[tid + 256] = s.v1;
        dst[tid + 512] = s.v2;
        dst[tid + 768] = s.v3;
        if (tid < NTASK - 1024) dst[tid + 1024] = s.v4;
    };

    // ---- Prologue: stage tile 0, issue tile-1 loads ----
    Stage rg = load_tile(y0);
    store_stage(rg);                 // compiler inserts the vmcnt wait
    rg = load_tile(y0 + TY);         // in flight across the whole tile-0 compute
    lgkm_barrier();

    const int k  = tid & 15;          // chunk col; global x = x0 + 4k
    const int ey = tid >> 4;          // row within tile
    const int rx = (k << 2) + 4;      // raw float col of x0+4k
    const int c  = k << 2;

    for (int tl = 0; tl < TPB; ++tl) {
        const int y0t = y0 + tl * TY;

        // ---- Phase 1: straight-line, 1 interior chunk per thread ----
        const f4    cC = *(const f4*)&scv[ey + 2][rx];
        const f4    cU = *(const f4*)&scv[ey + 1][rx];
        const f4    cD = *(const f4*)&scv[ey + 3][rx];
        const float cL = scv[ey + 2][rx - 1];
        const float cR = scv[ey + 2][rx + 4];

        const f4    iC = *(const f4*)&sci[ey + 2][rx];
        const f4    iU = *(const f4*)&sci[ey + 1][rx];
        const f4    iD = *(const f4*)&sci[ey + 3][rx];
        const float iL = sci[ey + 2][rx - 1];
        const float iR = sci[ey + 2][rx + 4];

        const f4    eC = *(const f4*)&seta[ey + 1][rx];
        const f4    eU = *(const f4*)&seta[ey][rx];
        const f4    eD = *(const f4*)&seta[ey + 2][rx];
        const float eL = seta[ey + 1][rx - 1];
        const float eR = seta[ey + 1][rx + 4];

        f4 dv, di, en;
        #pragma unroll
        for (int j = 0; j < 4; ++j) {
            const float c0 = cC[j];
            const float i0 = iC[j];
            const float e0 = eC[j];
            const float cl = (j == 0) ? cL : cC[j - 1];
            const float cr = (j == 3) ? cR : cC[j + 1];
            const float il = (j == 0) ? iL : iC[j - 1];
            const float ir = (j == 3) ? iR : iC[j + 1];
            const float el = (j == 0) ? eL : eC[j - 1];
            const float er = (j == 3) ? eR : eC[j + 1];

            const float lap_cv  = cl + cr + cU[j] + cD[j] - 4.0f * c0;
            const float lap_ci  = il + ir + iU[j] + iD[j] - 4.0f * i0;
            const float lap_eta = el + er + eU[j] + eD[j] - 4.0f * e0;

            const float h  = (e0 - 1.0f) * (e0 - 1.0f);
            const float jj = e0 * e0;
            const float cs = 1.0f - c0 - i0;
            const float lgv = lg2m(c0);
            const float lgi = lg2m(i0);
            const float lgs = lg2m(cs);

            dv[j] = h * (energy_v + kl * (lgv - lgs)) + jj * (2.0f * (c0 - 1.0f))
                  - kappa_v * lap_cv;
            di[j] = h * (energy_i + kl * (lgi - lgs)) + jj * (2.0f * i0)
                  - kappa_i * lap_ci;

            const float fs = energy_v * c0 + energy_i * i0
                           + kl * (c0 * lgv + i0 * lgi + cs * lgs);
            const float fv = (c0 - 1.0f) * (c0 - 1.0f) + i0 * i0;
            const float dF_deta = fs * 2.0f * (e0 - 1.0f) + fv * 2.0f * e0
                                - kappa_e * lap_eta;   // N_PARAM == 1.0
            en[j] = clip01(fmaf(-dtl, dF_deta, e0));
        }

        *(f4*)&sdv[ey][c] = dv;
        *(f4*)&sdi[ey][c] = di;

        lgkm_barrier();

        // ---- Phase 2: centers from registers; halo dF from dense LDS,
        //      tile-edge halo recomputed locally from the raw LDS. ----
        auto evalpt = [&](int cr, int cc, int er) -> float2 {
            const float c0 = scv[cr][cc];
            const float lap_cv = scv[cr][cc - 1] + scv[cr][cc + 1]
                               + scv[cr - 1][cc] + scv[cr + 1][cc] - 4.0f * c0;
            const float i0 = sci[cr][cc];
            const float lap_ci = sci[cr][cc - 1] + sci[cr][cc + 1]
                               + sci[cr - 1][cc] + sci[cr + 1][cc] - 4.0f * i0;
            const float e0 = seta[er][cc];
            const float h  = (e0 - 1.0f) * (e0 - 1.0f);
            const float jj = e0 * e0;
            const float cs = 1.0f - c0 - i0;
            const float lgv = lg2m(c0);
            const float lgi = lg2m(i0);
            const float lgs = lg2m(cs);
            const float dvx = h * (energy_v + kl * (lgv - lgs))
                            + jj * (2.0f * (c0 - 1.0f)) - kappa_v * lap_cv;
            const float dix = h * (energy_i + kl * (lgi - lgs))
                            + jj * (2.0f * i0) - kappa_i * lap_ci;
            return make_float2(dvx, dix);
        };

        float vL, wL, vR, wR;
        if (k == 0) {
            const float2 r = evalpt(ey + 2, 3, ey + 1);      // dF(x0-1)
            vL = r.x; wL = r.y;
        } else {
            vL = sdv[ey][c - 1]; wL = sdi[ey][c - 1];
        }
        if (k == 15) {
            const float2 r = evalpt(ey + 2, 68, ey + 1);     // dF(x0+64)
            vR = r.x; wR = r.y;
        } else {
            vR = sdv[ey][c + 4]; wR = sdi[ey][c + 4];
        }

        f4 vU, wU, vD, wD;
        if (ey == 0) {
            #pragma unroll
            for (int j = 0; j < 4; ++j) {                    // dF(y0t-1)
                const float2 r = evalpt(1, rx + j, 0);
                vU[j] = r.x; wU[j] = r.y;
            }
        } else {
            vU = *(const f4*)&sdv[ey - 1][c];
            wU = *(const f4*)&sdi[ey - 1][c];
        }
        if (ey == 15) {
            #pragma unroll
            for (int j = 0; j < 4; ++j) {                    // dF(y0t+16)
                const float2 r = evalpt(18, rx + j, 17);
                vD[j] = r.x; wD[j] = r.y;
            }
        } else {
            vD = *(const f4*)&sdv[ey + 1][c];
            wD = *(const f4*)&sdi[ey + 1][c];
        }

        const int gidx = bbase + ((y0t + ey) << LOG2W) + (x0 + c);  // interior
        f4 outv, outi;
        #pragma unroll
        for (int j = 0; j < 4; ++j) {
            const float lv = ((j == 0) ? vL : dv[j - 1]) + ((j == 3) ? vR : dv[j + 1])
                           + vU[j] + vD[j] - 4.0f * dv[j];
            const float li = ((j == 0) ? wL : di[j - 1]) + ((j == 3) ? wR : di[j + 1])
                           + wU[j] + wD[j] - 4.0f * di[j];
            outv[j] = clip01(fmaf(dtrv * cC[j], lv, cC[j]));
            outi[j] = clip01(fmaf(dtri * iC[j], li, iC[j]));
        }
        __builtin_nontemporal_store(en,   (f4*)(eta_new + gidx));
        __builtin_nontemporal_store(outv, (f4*)(cv_new + gidx));
        __builtin_nontemporal_store(outi, (f4*)(ci_new + gidx));

        // ---- Rotate the pipeline: LDS <- regs(tile tl+1); issue tl+2 loads ----
        if (tl + 1 < TPB) {
            lgkm_barrier();              // all waves done reading LDS for tile tl
            store_stage(rg);             // waits (counted) for rg's loads only
            if (tl + 2 < TPB) rg = load_tile(y0 + (tl + 2) * TY);
            lgkm_barrier();              // raw LDS for tile tl+1 ready
        }
    }
}

extern "C" void kernel_launch(void* const* d_in, const int* in_sizes, int n_in,
                              void* d_out, int out_size, void* d_ws, size_t ws_size,
                              hipStream_t stream) {
    // Input order: cv, ci, eta, energy_v0, energy_i0, kBT0, kappa_v0, kappa_i0,
    //              kappa_eta0, diff_v0, diff_i0, L0  — all float32 per reference.
    const float* cv  = (const float*)d_in[0];
    const float* ci  = (const float*)d_in[1];
    const float* eta = (const float*)d_in[2];
    const float* p_ev  = (const float*)d_in[3];
    const float* p_ei  = (const float*)d_in[4];
    const float* p_kbt = (const float*)d_in[5];
    const float* p_kv  = (const float*)d_in[6];
    const float* p_ki  = (const float*)d_in[7];
    const float* p_ke  = (const float*)d_in[8];
    const float* p_dv  = (const float*)d_in[9];
    const float* p_di  = (const float*)d_in[10];
    const float* p_L   = (const float*)d_in[11];

    const int N = in_sizes[0];  // 8*1024*1024 elements

    float* out     = (float*)d_out;
    float* cv_new  = out;
    float* ci_new  = out + N;
    float* eta_new = out + 2 * N;

    const dim3 block(256);
    const dim3 grid(1024 / TX, 1024 / (TY * TPB), N / HW);  // (16, 16, 8)

    irr_fused<<<grid, block, 0, stream>>>(cv, ci, eta, p_ev, p_ei, p_kbt,
                                          p_kv, p_ki, p_ke, p_dv, p_di, p_L,
                                          cv_new, ci_new, eta_new);
}

// Round 6
// 216.974 us; speedup vs baseline: 1.8302x; 1.8302x over previous
//
#include <hip/hip_runtime.h>

// Problem geometry (fixed by the reference): B=8, H=1024, W=1024, periodic.
#define WMASK 1023
#define LOG2W 10
#define HW (1024 * 1024)

#define EPS 1e-6f
#define DT 1e-2f

// Output tile 64x16, 256 threads, 1 float4 of output per thread per tile.
// Each block sweeps TPB=4 vertically-adjacent tiles. Raw fields are staged by
// global_load_lds DMA (no VGPR round-trip -> no spills, unlike R5) into a
// double buffer: tile n+1's loads are in flight across tile n's compute; the
// only vmcnt(0) drain is once per tile at the rotation barrier.
#define TX 64
#define TY 16
#define TPB 4

// Raw tile, f4-task-indexed, LDS float offset of task t is exactly 4t:
//   cv  tasks [0,360):   x [x0-4,x0+67] (18 chunks, row stride 72), y [-2,+17]
//   ci  tasks [360,720)
//   eta tasks [720,1044): y [-1,+16] (18 rows)
#define RST 72
#define NTASK 1044
#define RAWF (NTASK * 4)     // 4176 floats = 16704 B per buffer
#define CI_OFF 1440
#define ETA_OFF 2880
// dF tiles: interior only, 16 chunks x 16 rows, dense stride 64.
#define SST 64
// LDS: 2*16704 + 2*4096 = 41600 B -> 3 blocks/CU (12 waves).

typedef float f4 __attribute__((ext_vector_type(4)));
typedef unsigned int u32;

__device__ __forceinline__ float scal(const float* __restrict__ p) {
    return fabsf(p[0]) + 0.001f;
}
__device__ __forceinline__ float clip01(float v) {
    return fminf(fmaxf(v, 0.0f), 1.0f);
}
// log2 of clamped arg; caller folds ln2 into the kBT scalar (kl).
__device__ __forceinline__ float lg2m(float m) {
    return __log2f(fmaxf(m, EPS));   // jnp.log(where(m<eps,eps,m)) == ln2*log2(max(m,eps))
}

// Barrier waiting only this wave's LDS ops (no vmcnt drain).
__device__ __forceinline__ void lgkm_barrier() {
    asm volatile("s_waitcnt lgkmcnt(0)" ::: "memory");
    __builtin_amdgcn_s_barrier();
}
// Rotation barrier: own vmem (DMA loads + stores) drained, then sync.
__device__ __forceinline__ void vm_barrier() {
    asm volatile("s_waitcnt vmcnt(0)" ::: "memory");
    __builtin_amdgcn_s_barrier();
}

// 16B global -> LDS DMA. LDS dest is wave-uniform base + lane*16 (our task
// layout is linear in tid, satisfying this).
__device__ __forceinline__ void gld16(const float* g, float* l) {
    __builtin_amdgcn_global_load_lds(
        (const __attribute__((address_space(1))) u32*)g,
        (__attribute__((address_space(3))) u32*)l, 16, 0, 0);
}

__global__ __launch_bounds__(256, 3) void irr_fused(
    const float* __restrict__ cv,
    const float* __restrict__ ci,
    const float* __restrict__ eta,
    const float* __restrict__ p_ev,
    const float* __restrict__ p_ei,
    const float* __restrict__ p_kbt,
    const float* __restrict__ p_kv,
    const float* __restrict__ p_ki,
    const float* __restrict__ p_ke,
    const float* __restrict__ p_dv,
    const float* __restrict__ p_di,
    const float* __restrict__ p_L,
    float* __restrict__ cv_new,
    float* __restrict__ ci_new,
    float* __restrict__ eta_new)
{
    __shared__ __attribute__((aligned(16))) float sraw[2][RAWF];
    __shared__ __attribute__((aligned(16))) float sdv[16][SST];
    __shared__ __attribute__((aligned(16))) float sdi[16][SST];

    const int tid = threadIdx.x;
    const int x0 = blockIdx.x * TX;
    const int y0 = blockIdx.y * (TY * TPB);
    const int bbase = blockIdx.z * HW;

    const float energy_v = scal(p_ev);
    const float energy_i = scal(p_ei);
    const float kBT      = scal(p_kbt);
    const float kappa_v  = scal(p_kv);
    const float kappa_i  = scal(p_ki);
    const float kappa_e  = scal(p_ke);
    const float diff_v   = scal(p_dv);
    const float diff_i   = scal(p_di);
    const float L        = scal(p_L);
    const float kl   = kBT * 0.69314718056f;   // kBT*ln2: folds log2->ln
    const float dtl  = DT * L;
    const float dtrv = DT * diff_v / kBT;      // DT * mv / cv
    const float dtri = DT * diff_i / kBT;

    // ---- Per-thread task descriptors (tile-invariant): src + gx folded, row
    //      offset relative to y0t. Statically indexed -> registers. ----
    const float* tsrc[5];
    int trow[5];
    #pragma unroll
    for (int i = 0; i < 5; ++i) {
        const int t = tid + (i << 8);
        if (i == 4 && tid >= NTASK - 1024) { tsrc[i] = cv; trow[i] = 0; continue; }
        const float* src; int r, ry0;
        if (t < 360)      { src = cv;  r = t;       ry0 = -2; }
        else if (t < 720) { src = ci;  r = t - 360; ry0 = -2; }
        else              { src = eta; r = t - 720; ry0 = -1; }
        const int cx = r % 18;
        const int cy = r / 18;
        tsrc[i] = src + bbase + ((x0 - 4 + (cx << 2)) & WMASK);
        trow[i] = ry0 + cy;
    }

    auto stage_async = [&](int b, int y0t) {
        #pragma unroll
        for (int i = 0; i < 5; ++i) {
            if (i < 4 || tid < NTASK - 1024) {
                const int gy = (trow[i] + y0t) & WMASK;
                gld16(tsrc[i] + (gy << LOG2W), &sraw[b][(tid + (i << 8)) << 2]);
            }
        }
    };

    int cur = 0;
    stage_async(0, y0);
    vm_barrier();

    const int k  = tid & 15;          // chunk col; global x = x0 + 4k
    const int ey = tid >> 4;          // row within tile
    const int rx = (k << 2) + 4;      // raw float col of x0+4k
    const int c  = k << 2;

    for (int tl = 0; tl < TPB; ++tl) {
        const int y0t = y0 + tl * TY;

        // ---- Prefetch next tile into the other buffer (in flight all tile) ----
        if (tl + 1 < TPB) stage_async(cur ^ 1, y0 + (tl + 1) * TY);

        // ---- Phase 1: straight-line, 1 interior chunk per thread.
        //      All f4 reads are dense/contiguous per wave (conflict-free);
        //      x-neighbor scalars come from lane+-1 via shuffle. ----
        const f4 cC = *(const f4*)&sraw[cur][(ey + 2) * RST + rx];
        const f4 cU = *(const f4*)&sraw[cur][(ey + 1) * RST + rx];
        const f4 cD = *(const f4*)&sraw[cur][(ey + 3) * RST + rx];
        const f4 iC = *(const f4*)&sraw[cur][CI_OFF + (ey + 2) * RST + rx];
        const f4 iU = *(const f4*)&sraw[cur][CI_OFF + (ey + 1) * RST + rx];
        const f4 iD = *(const f4*)&sraw[cur][CI_OFF + (ey + 3) * RST + rx];
        const f4 eC = *(const f4*)&sraw[cur][ETA_OFF + (ey + 1) * RST + rx];
        const f4 eU = *(const f4*)&sraw[cur][ETA_OFF + (ey)     * RST + rx];
        const f4 eD = *(const f4*)&sraw[cur][ETA_OFF + (ey + 2) * RST + rx];

        float cL = __shfl_up(cC[3], 1), cR = __shfl_down(cC[0], 1);
        float iL = __shfl_up(iC[3], 1), iR = __shfl_down(iC[0], 1);
        float eL = __shfl_up(eC[3], 1), eR = __shfl_down(eC[0], 1);
        if (k == 0) {        // lane has no left neighbor in-row: read col 3 (x0-1)
            cL = sraw[cur][(ey + 2) * RST + 3];
            iL = sraw[cur][CI_OFF + (ey + 2) * RST + 3];
            eL = sraw[cur][ETA_OFF + (ey + 1) * RST + 3];
        }
        if (k == 15) {       // col 68 (x0+64)
            cR = sraw[cur][(ey + 2) * RST + 68];
            iR = sraw[cur][CI_OFF + (ey + 2) * RST + 68];
            eR = sraw[cur][ETA_OFF + (ey + 1) * RST + 68];
        }

        f4 dv, di, en;
        #pragma unroll
        for (int j = 0; j < 4; ++j) {
            const float c0 = cC[j];
            const float i0 = iC[j];
            const float e0 = eC[j];
            const float cl = (j == 0) ? cL : cC[j - 1];
            const float cr = (j == 3) ? cR : cC[j + 1];
            const float il = (j == 0) ? iL : iC[j - 1];
            const float ir = (j == 3) ? iR : iC[j + 1];
            const float el = (j == 0) ? eL : eC[j - 1];
            const float er = (j == 3) ? eR : eC[j + 1];

            const float lap_cv  = cl + cr + cU[j] + cD[j] - 4.0f * c0;
            const float lap_ci  = il + ir + iU[j] + iD[j] - 4.0f * i0;
            const float lap_eta = el + er + eU[j] + eD[j] - 4.0f * e0;

            const float h  = (e0 - 1.0f) * (e0 - 1.0f);
            const float jj = e0 * e0;
            const float cs = 1.0f - c0 - i0;
            const float lgv = lg2m(c0);
            const float lgi = lg2m(i0);
            const float lgs = lg2m(cs);

            dv[j] = h * (energy_v + kl * (lgv - lgs)) + jj * (2.0f * (c0 - 1.0f))
                  - kappa_v * lap_cv;
            di[j] = h * (energy_i + kl * (lgi - lgs)) + jj * (2.0f * i0)
                  - kappa_i * lap_ci;

            const float fs = energy_v * c0 + energy_i * i0
                           + kl * (c0 * lgv + i0 * lgi + cs * lgs);
            const float fv = (c0 - 1.0f) * (c0 - 1.0f) + i0 * i0;
            const float dF_deta = fs * 2.0f * (e0 - 1.0f) + fv * 2.0f * e0
                                - kappa_e * lap_eta;   // N_PARAM == 1.0
            en[j] = clip01(fmaf(-dtl, dF_deta, e0));
        }

        *(f4*)&sdv[ey][c] = dv;
        *(f4*)&sdi[ey][c] = di;

        // x-halo dF via shuffle (lane+-1's dv/di registers)
        float vL = __shfl_up(dv[3], 1), vR = __shfl_down(dv[0], 1);
        float wL = __shfl_up(di[3], 1), wR = __shfl_down(di[0], 1);

        lgkm_barrier();   // sdv/sdi visible; prefetch DMA stays in flight

        // ---- Phase 2: centers from registers; y-halo dF from dense LDS;
        //      tile-edge halo recomputed locally from the raw LDS. ----
        auto evalpt = [&](int cr, int cc, int er) -> float2 {
            const float c0 = sraw[cur][cr * RST + cc];
            const float lap_cv = sraw[cur][cr * RST + cc - 1]
                               + sraw[cur][cr * RST + cc + 1]
                               + sraw[cur][(cr - 1) * RST + cc]
                               + sraw[cur][(cr + 1) * RST + cc] - 4.0f * c0;
            const float i0 = sraw[cur][CI_OFF + cr * RST + cc];
            const float lap_ci = sraw[cur][CI_OFF + cr * RST + cc - 1]
                               + sraw[cur][CI_OFF + cr * RST + cc + 1]
                               + sraw[cur][CI_OFF + (cr - 1) * RST + cc]
                               + sraw[cur][CI_OFF + (cr + 1) * RST + cc] - 4.0f * i0;
            const float e0 = sraw[cur][ETA_OFF + er * RST + cc];
            const float h  = (e0 - 1.0f) * (e0 - 1.0f);
            const float jj = e0 * e0;
            const float cs = 1.0f - c0 - i0;
            const float lgv = lg2m(c0);
            const float lgi = lg2m(i0);
            const float lgs = lg2m(cs);
            const float dvx = h * (energy_v + kl * (lgv - lgs))
                            + jj * (2.0f * (c0 - 1.0f)) - kappa_v * lap_cv;
            const float dix = h * (energy_i + kl * (lgi - lgs))
                            + jj * (2.0f * i0) - kappa_i * lap_ci;
            return make_float2(dvx, dix);
        };

        if (k == 0) {
            const float2 r = evalpt(ey + 2, 3, ey + 1);      // dF(x0-1)
            vL = r.x; wL = r.y;
        }
        if (k == 15) {
            const float2 r = evalpt(ey + 2, 68, ey + 1);     // dF(x0+64)
            vR = r.x; wR = r.y;
        }

        f4 vU, wU, vD, wD;
        if (ey == 0) {
            #pragma unroll
            for (int j = 0; j < 4; ++j) {                    // dF(y0t-1)
                const float2 r = evalpt(1, rx + j, 0);
                vU[j] = r.x; wU[j] = r.y;
            }
        } else {
            vU = *(const f4*)&sdv[ey - 1][c];
            wU = *(const f4*)&sdi[ey - 1][c];
        }
        if (ey == 15) {
            #pragma unroll
            for (int j = 0; j < 4; ++j) {                    // dF(y0t+16)
                const float2 r = evalpt(18, rx + j, 17);
                vD[j] = r.x; wD[j] = r.y;
            }
        } else {
            vD = *(const f4*)&sdv[ey + 1][c];
            wD = *(const f4*)&sdi[ey + 1][c];
        }

        const int gidx = bbase + ((y0t + ey) << LOG2W) + (x0 + c);  // interior
        f4 outv, outi;
        #pragma unroll
        for (int j = 0; j < 4; ++j) {
            const float lv = ((j == 0) ? vL : dv[j - 1]) + ((j == 3) ? vR : dv[j + 1])
                           + vU[j] + vD[j] - 4.0f * dv[j];
            const float li = ((j == 0) ? wL : di[j - 1]) + ((j == 3) ? wR : di[j + 1])
                           + wU[j] + wD[j] - 4.0f * di[j];
            outv[j] = clip01(fmaf(dtrv * cC[j], lv, cC[j]));
            outi[j] = clip01(fmaf(dtri * iC[j], li, iC[j]));
        }
        __builtin_nontemporal_store(en,   (f4*)(eta_new + gidx));
        __builtin_nontemporal_store(outv, (f4*)(cv_new + gidx));
        __builtin_nontemporal_store(outi, (f4*)(ci_new + gidx));

        // ---- Rotation: prefetch (whole compute to land) + stores drained,
        //      then swap. Also fences tile tl's sdv/raw reads vs tl+1 writes. ----
        if (tl + 1 < TPB) {
            vm_barrier();
            cur ^= 1;
        }
    }
}

extern "C" void kernel_launch(void* const* d_in, const int* in_sizes, int n_in,
                              void* d_out, int out_size, void* d_ws, size_t ws_size,
                              hipStream_t stream) {
    // Input order: cv, ci, eta, energy_v0, energy_i0, kBT0, kappa_v0, kappa_i0,
    //              kappa_eta0, diff_v0, diff_i0, L0  — all float32 per reference.
    const float* cv  = (const float*)d_in[0];
    const float* ci  = (const float*)d_in[1];
    const float* eta = (const float*)d_in[2];
    const float* p_ev  = (const float*)d_in[3];
    const float* p_ei  = (const float*)d_in[4];
    const float* p_kbt = (const float*)d_in[5];
    const float* p_kv  = (const float*)d_in[6];
    const float* p_ki  = (const float*)d_in[7];
    const float* p_ke  = (const float*)d_in[8];
    const float* p_dv  = (const float*)d_in[9];
    const float* p_di  = (const float*)d_in[10];
    const float* p_L   = (const float*)d_in[11];

    const int N = in_sizes[0];  // 8*1024*1024 elements

    float* out     = (float*)d_out;
    float* cv_new  = out;
    float* ci_new  = out + N;
    float* eta_new = out + 2 * N;

    const dim3 block(256);
    const dim3 grid(1024 / TX, 1024 / (TY * TPB), N / HW);  // (16, 16, 8)

    irr_fused<<<grid, block, 0, stream>>>(cv, ci, eta, p_ev, p_ei, p_kbt,
                                          p_kv, p_ki, p_ke, p_dv, p_di, p_L,
                                          cv_new, ci_new, eta_new);
}